// Round 1
// baseline (3985.828 us; speedup 1.0000x reference)
//
#include <hip/hip_runtime.h>
#include <math.h>

#define N_NODES 30000
#define N_EDGES 480000
#define EW 7500            // edge-kernel waves
#define EB 1875            // edge-kernel blocks (4 waves each)
#define TILES_PER_WAVE 4   // 7500*4 = 30000 tiles of 16 edges

typedef __attribute__((ext_vector_type(8))) short s8v;   // 8 x bf16 (as i16 bits)
typedef __attribute__((ext_vector_type(4))) float f4v;

__device__ inline unsigned short f2bf(float f) {
  union { float f; unsigned u; } v; v.f = f;
  return (unsigned short)((v.u + 0x7fffu + ((v.u >> 16) & 1u)) >> 16);  // RNE
}
__device__ inline float sspf(float x) {  // softplus(x) - log(2)
  return fmaxf(x, 0.f) + log1pf(expf(-fabsf(x))) - 0.69314718055994531f;
}

// ---------------- node_pre: s1 = s@lin1_s/sqrt32 ; v1 = v@lin1_v/sqrt32 ----------------
// s1v1 layout per node (128 floats): [0:32]=s1[m], [32+3m+c]=v1[m][c]  (mirrors x layout)
__global__ __launch_bounds__(256) void k_node_pre(const float* __restrict__ x,
    const float* __restrict__ l1s, const float* __restrict__ l1v,
    float* __restrict__ s1v1)
{
  int t = blockIdx.x * 256 + threadIdx.x;
  int node = t >> 7, j = t & 127;
  const float* xr = x + (size_t)node * 128;
  float acc = 0.f;
  if (j < 32) {
#pragma unroll
    for (int u = 0; u < 32; ++u) acc += xr[u] * l1s[u * 32 + j];
  } else {
    int jj = j - 32, m = jj / 3, c = jj - 3 * m;
#pragma unroll
    for (int u = 0; u < 32; ++u) acc += xr[32 + u * 3 + c] * l1v[u * 32 + m];
  }
  s1v1[t] = acc * 0.17677669529663689f;
}

// ---------------- edge kernel: fused 3-stage MLP (bf16 MFMA) + messages + atomic agg ----------------
// One wave = 16 edges. A-frag: row=lane&15, k=8*(lane>>4)+i. B-frag: col=lane&15, same k.
// C/D: col=lane&15, row=(lane>>4)*4+i.
// agg layout per node (256 floats): [0:32]=m_s1, [32:64]=m_s2, [64+3m+c]=m_v1, [160+3m+c]=m_v2
__global__ __launch_bounds__(256, 2) void k_edge(
    const float* __restrict__ esc, const int* __restrict__ esrc, const int* __restrict__ edst,
    const float* __restrict__ eattr, const float* __restrict__ s1v1,
    const float* __restrict__ w1g, const float* __restrict__ w2g, const float* __restrict__ w3g,
    float* __restrict__ agg)
{
  __shared__ __attribute__((aligned(16))) unsigned short W2T[64 * 72];   // [n][k] padded
  __shared__ __attribute__((aligned(16))) unsigned short W3T[128 * 72];  // [n][k] padded
  __shared__ __attribute__((aligned(16))) unsigned short Hb[4][2][16 * 72];

  const int tid = threadIdx.x, lane = tid & 63, wv = tid >> 6;
  const int c0 = lane & 15, g = lane >> 4;

  for (int idx = tid; idx < 64 * 64; idx += 256) {
    int k = idx >> 6, n2 = idx & 63;
    W2T[n2 * 72 + k] = f2bf(w2g[idx]);
  }
  for (int idx = tid; idx < 64 * 128; idx += 256) {
    int k = idx >> 7, n2 = idx & 127;
    W3T[n2 * 72 + k] = f2bf(w3g[idx]);
  }
  s8v B1[4];
#pragma unroll
  for (int nt = 0; nt < 4; ++nt)
#pragma unroll
    for (int i = 0; i < 8; ++i)
      B1[nt][i] = (g == 0) ? (short)f2bf(w1g[i * 64 + nt * 16 + c0]) : (short)0;
  __syncthreads();

  unsigned short* h1 = &Hb[wv][0][0];
  unsigned short* h2 = &Hb[wv][1][0];
  const f4v z = {0.f, 0.f, 0.f, 0.f};
  const int gw = blockIdx.x * 4 + wv;

  for (int it = 0; it < TILES_PER_WAVE; ++it) {
    int tile = gw + it * EW;
    int e0 = tile * 16;
    // ---- stage 1: h1 = ssp(es @ W1 / sqrt(8)), K=8 padded into K=32
    s8v A1 = {0, 0, 0, 0, 0, 0, 0, 0};
    if (g == 0) {
      const float4* p = (const float4*)(esc + (size_t)(e0 + c0) * 8);
      float4 a = p[0], b = p[1];
      A1[0] = (short)f2bf(a.x); A1[1] = (short)f2bf(a.y);
      A1[2] = (short)f2bf(a.z); A1[3] = (short)f2bf(a.w);
      A1[4] = (short)f2bf(b.x); A1[5] = (short)f2bf(b.y);
      A1[6] = (short)f2bf(b.z); A1[7] = (short)f2bf(b.w);
    }
#pragma unroll
    for (int nt = 0; nt < 4; ++nt) {
      f4v acc = __builtin_amdgcn_mfma_f32_16x16x32_bf16(A1, B1[nt], z, 0, 0, 0);
#pragma unroll
      for (int i = 0; i < 4; ++i)
        h1[(g * 4 + i) * 72 + nt * 16 + c0] = f2bf(sspf(acc[i] * 0.35355339059327373f));
    }
    __syncthreads();
    // ---- stage 2: h2 = ssp(h1 @ W2 / 8)
    s8v A2a = *(const s8v*)&h1[c0 * 72 + 8 * g];
    s8v A2b = *(const s8v*)&h1[c0 * 72 + 32 + 8 * g];
#pragma unroll
    for (int nt = 0; nt < 4; ++nt) {
      s8v Ba = *(const s8v*)&W2T[(nt * 16 + c0) * 72 + 8 * g];
      s8v Bb = *(const s8v*)&W2T[(nt * 16 + c0) * 72 + 32 + 8 * g];
      f4v acc = __builtin_amdgcn_mfma_f32_16x16x32_bf16(A2a, Ba, z, 0, 0, 0);
      acc = __builtin_amdgcn_mfma_f32_16x16x32_bf16(A2b, Bb, acc, 0, 0, 0);
#pragma unroll
      for (int i = 0; i < 4; ++i)
        h2[(g * 4 + i) * 72 + nt * 16 + c0] = f2bf(sspf(acc[i] * 0.125f));
    }
    __syncthreads();
    // ---- stage 3: w = h2 @ W3 / 8  (kept in C-frags)
    s8v A3a = *(const s8v*)&h2[c0 * 72 + 8 * g];
    s8v A3b = *(const s8v*)&h2[c0 * 72 + 32 + 8 * g];
    f4v acc3[8];
#pragma unroll
    for (int nt = 0; nt < 8; ++nt) {
      s8v Ba = *(const s8v*)&W3T[(nt * 16 + c0) * 72 + 8 * g];
      s8v Bb = *(const s8v*)&W3T[(nt * 16 + c0) * 72 + 32 + 8 * g];
      acc3[nt] = __builtin_amdgcn_mfma_f32_16x16x32_bf16(A3a, Ba, z, 0, 0, 0);
      acc3[nt] = __builtin_amdgcn_mfma_f32_16x16x32_bf16(A3b, Bb, acc3[nt], 0, 0, 0);
    }
    // ---- epilogue: messages + atomic scatter. col = nt*16+c0 -> p=nt>>1, m=(nt&1)*16+c0
#pragma unroll
    for (int i = 0; i < 4; ++i) {
      int e = e0 + g * 4 + i;
      int src = esrc[e], dst = edst[e];
      float4 y = *(const float4*)(eattr + (size_t)e * 4);
      const float* svp = s1v1 + (size_t)src * 128;
      int mA = c0, mB = c0 + 16;
      float sA = svp[mA], sB = svp[mB];
      float vA0 = svp[32 + 3 * mA], vA1 = svp[33 + 3 * mA], vA2 = svp[34 + 3 * mA];
      float vB0 = svp[32 + 3 * mB], vB1 = svp[33 + 3 * mB], vB2 = svp[34 + 3 * mB];
      float* ad = agg + (size_t)dst * 256;
      float w0 = acc3[0][i] * 0.125f, w1_ = acc3[1][i] * 0.125f;
      float w2_ = acc3[2][i] * 0.125f, w3_ = acc3[3][i] * 0.125f;
      float w4_ = acc3[4][i] * 0.125f, w5_ = acc3[5][i] * 0.125f;
      float w6_ = acc3[6][i] * 0.125f, w7_ = acc3[7][i] * 0.125f;
      atomicAdd(ad + mA, w0 * sA * y.x);                                   // m_s1
      atomicAdd(ad + mB, w1_ * sB * y.x);
      atomicAdd(ad + 32 + mA, w6_ * (vA0 * y.y + vA1 * y.z + vA2 * y.w));  // m_s2
      atomicAdd(ad + 32 + mB, w7_ * (vB0 * y.y + vB1 * y.z + vB2 * y.w));
      atomicAdd(ad + 64 + 3 * mA + 0, w2_ * sA * y.y);                     // m_v1
      atomicAdd(ad + 64 + 3 * mA + 1, w2_ * sA * y.z);
      atomicAdd(ad + 64 + 3 * mA + 2, w2_ * sA * y.w);
      atomicAdd(ad + 64 + 3 * mB + 0, w3_ * sB * y.y);
      atomicAdd(ad + 64 + 3 * mB + 1, w3_ * sB * y.z);
      atomicAdd(ad + 64 + 3 * mB + 2, w3_ * sB * y.w);
      atomicAdd(ad + 160 + 3 * mA + 0, w4_ * vA0 * y.x);                   // m_v2
      atomicAdd(ad + 160 + 3 * mA + 1, w4_ * vA1 * y.x);
      atomicAdd(ad + 160 + 3 * mA + 2, w4_ * vA2 * y.x);
      atomicAdd(ad + 160 + 3 * mB + 0, w5_ * vB0 * y.x);
      atomicAdd(ad + 160 + 3 * mB + 1, w5_ * vB1 * y.x);
      atomicAdd(ad + 160 + 3 * mB + 2, w5_ * vB2 * y.x);
    }
    __syncthreads();
  }
}

// ---------------- node_post: lin2 + self-connection + gate + residual (4 nodes / wave) ----------------
__global__ __launch_bounds__(64) void k_node_post(
    const float* __restrict__ x, const float* __restrict__ attr, const float* __restrict__ agg,
    const float* __restrict__ l2s, const float* __restrict__ l2v,
    const float* __restrict__ scs, const float* __restrict__ scv,
    float* __restrict__ out)
{
  __shared__ float xa[4][136];   // x row (128) + attr (8)
  __shared__ float ag[4][256];
  __shared__ float ops[256];     // s[u]*attr[a]
  __shared__ float opv[768];     // v[u][c]*attr[a], c-major blocks of 256
  const int l = threadIdx.x;
  const int n0 = blockIdx.x * 4;
#pragma unroll
  for (int b = 0; b < 4; ++b) {
    int nd = n0 + b;
    xa[b][l] = x[(size_t)nd * 128 + l];
    xa[b][64 + l] = x[(size_t)nd * 128 + 64 + l];
    if (l < 8) xa[b][128 + l] = attr[nd * 8 + l];
#pragma unroll
    for (int q = 0; q < 4; ++q) ag[b][q * 64 + l] = agg[(size_t)nd * 256 + q * 64 + l];
  }
  __syncthreads();
  for (int b = 0; b < 4; ++b) {
    int nd = n0 + b;
    for (int k = l; k < 256; k += 64) { int u = k >> 3, a = k & 7; ops[k] = xa[b][u] * xa[b][128 + a]; }
    for (int k = l; k < 768; k += 64) {
      int c = k >> 8, kk = k & 255; int u = kk >> 3, a = kk & 7;
      opv[k] = xa[b][32 + 3 * u + c] * xa[b][128 + a];
    }
    __syncthreads();
    // out_s[l] (64 outputs) ; scale: lin2 path 0.125*0.25, sc path 1/16
    float acc = 0.f, sa = 0.f;
#pragma unroll 8
    for (int u = 0; u < 64; ++u) acc += ag[b][u] * l2s[u * 64 + l];
#pragma unroll 8
    for (int k = 0; k < 256; ++k) sa += ops[k] * scs[k * 64 + l];
    float outs = acc * 0.03125f + sa * 0.0625f;
    float gss = sspf(outs);
    // vec outputs: flat f1=l for all lanes, f2=64+l for lanes<32 (flat = w*3+c)
    int w1 = l / 3, c1 = l - 3 * w1;
    float av = 0.f, svv = 0.f;
#pragma unroll 8
    for (int u = 0; u < 64; ++u) av += ag[b][64 + 3 * u + c1] * l2v[u * 32 + w1];
#pragma unroll 8
    for (int k = 0; k < 256; ++k) svv += opv[c1 * 256 + k] * scv[k * 32 + w1];
    float ov1 = av * 0.03125f + svv * 0.0625f;
    int f2 = 64 + l;
    int w2 = f2 / 3, c2 = f2 - 3 * w2;
    float av2 = 0.f, sv2 = 0.f;
    if (l < 32) {
#pragma unroll 8
      for (int u = 0; u < 64; ++u) av2 += ag[b][64 + 3 * u + c2] * l2v[u * 32 + w2];
#pragma unroll 8
      for (int k = 0; k < 256; ++k) sv2 += opv[c2 * 256 + k] * scv[k * 32 + w2];
    }
    float ov2 = av2 * 0.03125f + sv2 * 0.0625f;
    float gate1 = __shfl(gss, 32 + w1, 64);
    float gate2 = __shfl(gss, 32 + w2, 64);
    float* o = out + (size_t)nd * 128;
    if (l < 32) o[l] = xa[b][l] + gss;            // scalars
    o[32 + l] = xa[b][32 + l] + ov1 * gate1;      // gated vec, flat l
    if (l < 32) o[96 + l] = xa[b][96 + l] + ov2 * gate2;  // gated vec, flat 64+l
    __syncthreads();
  }
}

extern "C" void kernel_launch(void* const* d_in, const int* in_sizes, int n_in,
                              void* d_out, int out_size, void* d_ws, size_t ws_size,
                              hipStream_t stream) {
  const float* node_input = (const float*)d_in[0];
  const float* node_attr  = (const float*)d_in[1];
  const int*   esrc  = (const int*)d_in[2];
  const int*   edst  = (const int*)d_in[3];
  const float* eattr = (const float*)d_in[4];
  const float* escal = (const float*)d_in[5];
  const float* l1s = (const float*)d_in[6];
  const float* l1v = (const float*)d_in[7];
  const float* w1  = (const float*)d_in[8];
  const float* w2  = (const float*)d_in[9];
  const float* w3  = (const float*)d_in[10];
  const float* l2s = (const float*)d_in[11];
  const float* l2v = (const float*)d_in[12];
  const float* scs = (const float*)d_in[13];
  const float* scv = (const float*)d_in[14];
  float* out  = (float*)d_out;
  float* s1v1 = (float*)d_ws;                       // 30000*128 f32
  float* agg  = s1v1 + (size_t)N_NODES * 128;       // 30000*256 f32

  for (int layer = 0; layer < 3; ++layer) {
    const float* xin = (layer == 0) ? node_input : (const float*)out;
    k_node_pre<<<N_NODES * 128 / 256, 256, 0, stream>>>(
        xin, l1s + layer * 1024, l1v + layer * 1024, s1v1);
    hipMemsetAsync(agg, 0, (size_t)N_NODES * 256 * sizeof(float), stream);
    k_edge<<<EB, 256, 0, stream>>>(escal, esrc, edst, eattr, s1v1,
        w1 + layer * 512, w2 + layer * 4096, w3 + layer * 8192, agg);
    k_node_post<<<N_NODES / 4, 64, 0, stream>>>(xin, node_attr, agg,
        l2s + layer * 4096, l2v + layer * 2048, scs + layer * 16384, scv + layer * 8192, out);
  }
}

// Round 2
// 2468.192 us; speedup vs baseline: 1.6149x; 1.6149x over previous
//
#include <hip/hip_runtime.h>
#include <math.h>

#define N_NODES 30000
#define N_EDGES 480000

typedef __attribute__((ext_vector_type(8))) short s8v;   // 8 x bf16 (as i16 bits)
typedef __attribute__((ext_vector_type(4))) float f4v;

__device__ inline unsigned short f2bf(float f) {
  union { float f; unsigned u; } v; v.f = f;
  return (unsigned short)((v.u + 0x7fffu + ((v.u >> 16) & 1u)) >> 16);  // RNE
}
__device__ inline float sspf(float x) {  // softplus(x) - log(2)
  return fmaxf(x, 0.f) + log1pf(expf(-fabsf(x))) - 0.69314718055994531f;
}

// ---------------- CSR build (once per launch; edge_dst identical across layers) ----------------
__global__ __launch_bounds__(256) void k_hist(const int* __restrict__ edst, int* __restrict__ counts) {
  int e = blockIdx.x * 256 + threadIdx.x;
  if (e < N_EDGES) atomicAdd(&counts[edst[e]], 1);
}

#define SCAN_T 1024
#define NPER 30   // 1024*30 = 30720 >= 30000
__global__ __launch_bounds__(1024) void k_scan(const int* __restrict__ counts,
                                               int* __restrict__ row_start, int* __restrict__ cursor) {
  __shared__ int part[SCAN_T];
  int t = threadIdx.x;
  int base = t * NPER;
  int local[NPER];
  int s = 0;
#pragma unroll
  for (int j = 0; j < NPER; ++j) {
    int idx = base + j;
    int c = (idx < N_NODES) ? counts[idx] : 0;
    local[j] = s;     // exclusive within chunk
    s += c;
  }
  part[t] = s;
  __syncthreads();
  for (int off = 1; off < SCAN_T; off <<= 1) {
    int v = (t >= off) ? part[t - off] : 0;
    __syncthreads();
    part[t] += v;
    __syncthreads();
  }
  int pre = (t == 0) ? 0 : part[t - 1];
#pragma unroll
  for (int j = 0; j < NPER; ++j) {
    int idx = base + j;
    if (idx < N_NODES) {
      int v = pre + local[j];
      row_start[idx] = v;
      cursor[idx] = v;
    }
  }
  if (t == SCAN_T - 1) row_start[N_NODES] = pre + s;
}

__global__ __launch_bounds__(256) void k_scatter(const int* __restrict__ edst,
                                                 int* __restrict__ cursor, int* __restrict__ eidx) {
  int e = blockIdx.x * 256 + threadIdx.x;
  if (e < N_EDGES) {
    int pos = atomicAdd(&cursor[edst[e]], 1);
    eidx[pos] = e;
  }
}

// ---------------- node_pre: s1 = s@lin1_s/sqrt32 ; v1 = v@lin1_v/sqrt32 ----------------
__global__ __launch_bounds__(256) void k_node_pre(const float* __restrict__ x,
    const float* __restrict__ l1s, const float* __restrict__ l1v,
    float* __restrict__ s1v1)
{
  int t = blockIdx.x * 256 + threadIdx.x;
  int node = t >> 7, j = t & 127;
  const float* xr = x + (size_t)node * 128;
  float acc = 0.f;
  if (j < 32) {
#pragma unroll
    for (int u = 0; u < 32; ++u) acc += xr[u] * l1s[u * 32 + j];
  } else {
    int jj = j - 32, m = jj / 3, c = jj - 3 * m;
#pragma unroll
    for (int u = 0; u < 32; ++u) acc += xr[32 + u * 3 + c] * l1v[u * 32 + m];
  }
  s1v1[t] = acc * 0.17677669529663689f;
}

// ---------------- fused edge MLP + per-node aggregation (1 wave = 1 dst node, no atomics) ----------
// MFMA frags: A row=lane&15, k=8*(lane>>4)+i. B col=lane&15. C/D col=lane&15, row=(lane>>4)*4+i.
// w cols: nt*16+c0 -> path p=(col>>5), m=col&31.
// agg layout per node (256 f): [0:32]=m_s1, [32:64]=m_s2, [64+3m+c]=m_v1, [160+3m+c]=m_v2
__global__ __launch_bounds__(256, 2) void k_edge_agg(
    const float* __restrict__ esc, const int* __restrict__ esrc,
    const float* __restrict__ eattr, const float* __restrict__ s1v1,
    const int* __restrict__ row_start, const int* __restrict__ eidx,
    const float* __restrict__ w1g, const float* __restrict__ w2g, const float* __restrict__ w3g,
    float* __restrict__ agg)
{
  __shared__ __attribute__((aligned(16))) unsigned short W2T[64 * 72];   // [n][k] padded
  __shared__ __attribute__((aligned(16))) unsigned short W3T[128 * 72];  // [n][k] padded
  __shared__ __attribute__((aligned(16))) unsigned short Hb[4][2][16 * 72];

  const int tid = threadIdx.x, lane = tid & 63, wv = tid >> 6;
  const int c0 = lane & 15, g = lane >> 4;

  for (int idx = tid; idx < 64 * 64; idx += 256) {
    int k = idx >> 6, n2 = idx & 63;
    W2T[n2 * 72 + k] = f2bf(w2g[idx]);
  }
  for (int idx = tid; idx < 64 * 128; idx += 256) {
    int k = idx >> 7, n2 = idx & 127;
    W3T[n2 * 72 + k] = f2bf(w3g[idx]);
  }
  s8v B1[4];
#pragma unroll
  for (int nt = 0; nt < 4; ++nt)
#pragma unroll
    for (int i = 0; i < 8; ++i)
      B1[nt][i] = (g == 0) ? (short)f2bf(w1g[i * 64 + nt * 16 + c0]) : (short)0;
  __syncthreads();   // only block-wide barrier (waves diverge after this)

  unsigned short* h1 = &Hb[wv][0][0];
  unsigned short* h2 = &Hb[wv][1][0];
  const f4v z = {0.f, 0.f, 0.f, 0.f};

  const int node = blockIdx.x * 4 + wv;
  const int jb = row_start[node], je = row_start[node + 1];

  float nacc[16];
#pragma unroll
  for (int k = 0; k < 16; ++k) nacc[k] = 0.f;

  for (int base = jb; base < je; base += 16) {
    const int nvalid = je - base;   // may exceed 16; slot s valid iff s < nvalid
    // ---- stage 1: h1 = ssp(es @ W1 / sqrt(8)), K=8 padded into K=32. Pad rows -> ssp(0)=0 -> w=0.
    s8v A1 = {0, 0, 0, 0, 0, 0, 0, 0};
    if (g == 0 && c0 < nvalid) {
      int eid = eidx[base + c0];
      const float4* p = (const float4*)(esc + (size_t)eid * 8);
      float4 a = p[0], b = p[1];
      A1[0] = (short)f2bf(a.x); A1[1] = (short)f2bf(a.y);
      A1[2] = (short)f2bf(a.z); A1[3] = (short)f2bf(a.w);
      A1[4] = (short)f2bf(b.x); A1[5] = (short)f2bf(b.y);
      A1[6] = (short)f2bf(b.z); A1[7] = (short)f2bf(b.w);
    }
#pragma unroll
    for (int nt = 0; nt < 4; ++nt) {
      f4v acc = __builtin_amdgcn_mfma_f32_16x16x32_bf16(A1, B1[nt], z, 0, 0, 0);
#pragma unroll
      for (int i = 0; i < 4; ++i)
        h1[(g * 4 + i) * 72 + nt * 16 + c0] = f2bf(sspf(acc[i] * 0.35355339059327373f));
    }
    // ---- stage 2: h2 = ssp(h1 @ W2 / 8)   (in-wave LDS dep; lgkmcnt handles ordering)
    s8v A2a = *(const s8v*)&h1[c0 * 72 + 8 * g];
    s8v A2b = *(const s8v*)&h1[c0 * 72 + 32 + 8 * g];
#pragma unroll
    for (int nt = 0; nt < 4; ++nt) {
      s8v Ba = *(const s8v*)&W2T[(nt * 16 + c0) * 72 + 8 * g];
      s8v Bb = *(const s8v*)&W2T[(nt * 16 + c0) * 72 + 32 + 8 * g];
      f4v acc = __builtin_amdgcn_mfma_f32_16x16x32_bf16(A2a, Ba, z, 0, 0, 0);
      acc = __builtin_amdgcn_mfma_f32_16x16x32_bf16(A2b, Bb, acc, 0, 0, 0);
#pragma unroll
      for (int i = 0; i < 4; ++i)
        h2[(g * 4 + i) * 72 + nt * 16 + c0] = f2bf(sspf(acc[i] * 0.125f));
    }
    // ---- stage 3: w = h2 @ W3 / 8
    s8v A3a = *(const s8v*)&h2[c0 * 72 + 8 * g];
    s8v A3b = *(const s8v*)&h2[c0 * 72 + 32 + 8 * g];
    f4v acc3[8];
#pragma unroll
    for (int nt = 0; nt < 8; ++nt) {
      s8v Ba = *(const s8v*)&W3T[(nt * 16 + c0) * 72 + 8 * g];
      s8v Bb = *(const s8v*)&W3T[(nt * 16 + c0) * 72 + 32 + 8 * g];
      acc3[nt] = __builtin_amdgcn_mfma_f32_16x16x32_bf16(A3a, Ba, z, 0, 0, 0);
      acc3[nt] = __builtin_amdgcn_mfma_f32_16x16x32_bf16(A3b, Bb, acc3[nt], 0, 0, 0);
    }
    // ---- epilogue: per-lane message partials for mA=c0, mB=c0+16 over this lane's 4 edge rows
    float msg[16];
#pragma unroll
    for (int k = 0; k < 16; ++k) msg[k] = 0.f;
#pragma unroll
    for (int i = 0; i < 4; ++i) {
      int s = g * 4 + i;
      float w0 = acc3[0][i] * 0.125f, w1_ = acc3[1][i] * 0.125f;
      float w2_ = acc3[2][i] * 0.125f, w3_ = acc3[3][i] * 0.125f;
      float w4_ = acc3[4][i] * 0.125f, w5_ = acc3[5][i] * 0.125f;
      float w6_ = acc3[6][i] * 0.125f, w7_ = acc3[7][i] * 0.125f;
      if (s < nvalid) {
        int eid = eidx[base + s];
        int src = esrc[eid];
        float4 y = *(const float4*)(eattr + (size_t)eid * 4);
        const float* svp = s1v1 + (size_t)src * 128;
        float sA = svp[c0], sB = svp[c0 + 16];
        float vA0 = svp[32 + 3 * c0], vA1 = svp[33 + 3 * c0], vA2 = svp[34 + 3 * c0];
        float vB0 = svp[80 + 3 * c0], vB1 = svp[81 + 3 * c0], vB2 = svp[82 + 3 * c0];
        msg[0] += w0 * sA * y.x;                                    // m_s1[mA]
        msg[1] += w1_ * sB * y.x;                                   // m_s1[mB]
        msg[2] += w6_ * (vA0 * y.y + vA1 * y.z + vA2 * y.w);        // m_s2[mA]
        msg[3] += w7_ * (vB0 * y.y + vB1 * y.z + vB2 * y.w);        // m_s2[mB]
        msg[4] += w2_ * sA * y.y;  msg[5] += w2_ * sA * y.z;  msg[6] += w2_ * sA * y.w;   // m_v1[mA]
        msg[7] += w3_ * sB * y.y;  msg[8] += w3_ * sB * y.z;  msg[9] += w3_ * sB * y.w;   // m_v1[mB]
        msg[10] += w4_ * vA0 * y.x; msg[11] += w4_ * vA1 * y.x; msg[12] += w4_ * vA2 * y.x; // m_v2[mA]
        msg[13] += w5_ * vB0 * y.x; msg[14] += w5_ * vB1 * y.x; msg[15] += w5_ * vB2 * y.x; // m_v2[mB]
      }
    }
    // ---- cross-lane reduce over the 4 g-groups (lanes l, l^16, l^32, l^48 share c0)
#pragma unroll
    for (int k = 0; k < 16; ++k) {
      float v = msg[k];
      v += __shfl_xor(v, 16, 64);
      v += __shfl_xor(v, 32, 64);
      nacc[k] += v;
    }
  }
  // ---- single write of the node's agg row (lanes 0..15 cover all 256 slots)
  if (g == 0) {
    float* ad = agg + (size_t)node * 256;
    ad[c0] = nacc[0];
    ad[16 + c0] = nacc[1];
    ad[32 + c0] = nacc[2];
    ad[48 + c0] = nacc[3];
#pragma unroll
    for (int c = 0; c < 3; ++c) {
      ad[64 + 3 * c0 + c]  = nacc[4 + c];    // m_v1[mA]
      ad[112 + 3 * c0 + c] = nacc[7 + c];    // m_v1[mB]
      ad[160 + 3 * c0 + c] = nacc[10 + c];   // m_v2[mA]
      ad[208 + 3 * c0 + c] = nacc[13 + c];   // m_v2[mB]
    }
  }
}

// ---------------- node_post: lin2 + self-connection + gate + residual (4 nodes / wave) ----------------
__global__ __launch_bounds__(64) void k_node_post(
    const float* __restrict__ x, const float* __restrict__ attr, const float* __restrict__ agg,
    const float* __restrict__ l2s, const float* __restrict__ l2v,
    const float* __restrict__ scs, const float* __restrict__ scv,
    float* __restrict__ out)
{
  __shared__ float xa[4][136];   // x row (128) + attr (8)
  __shared__ float ag[4][256];
  __shared__ float ops[256];     // s[u]*attr[a]
  __shared__ float opv[768];     // v[u][c]*attr[a], c-major blocks of 256
  const int l = threadIdx.x;
  const int n0 = blockIdx.x * 4;
#pragma unroll
  for (int b = 0; b < 4; ++b) {
    int nd = n0 + b;
    xa[b][l] = x[(size_t)nd * 128 + l];
    xa[b][64 + l] = x[(size_t)nd * 128 + 64 + l];
    if (l < 8) xa[b][128 + l] = attr[nd * 8 + l];
#pragma unroll
    for (int q = 0; q < 4; ++q) ag[b][q * 64 + l] = agg[(size_t)nd * 256 + q * 64 + l];
  }
  __syncthreads();
  for (int b = 0; b < 4; ++b) {
    int nd = n0 + b;
    for (int k = l; k < 256; k += 64) { int u = k >> 3, a = k & 7; ops[k] = xa[b][u] * xa[b][128 + a]; }
    for (int k = l; k < 768; k += 64) {
      int c = k >> 8, kk = k & 255; int u = kk >> 3, a = kk & 7;
      opv[k] = xa[b][32 + 3 * u + c] * xa[b][128 + a];
    }
    __syncthreads();
    float acc = 0.f, sa = 0.f;
#pragma unroll 8
    for (int u = 0; u < 64; ++u) acc += ag[b][u] * l2s[u * 64 + l];
#pragma unroll 8
    for (int k = 0; k < 256; ++k) sa += ops[k] * scs[k * 64 + l];
    float outs = acc * 0.03125f + sa * 0.0625f;
    float gss = sspf(outs);
    int w1 = l / 3, c1 = l - 3 * w1;
    float av = 0.f, svv = 0.f;
#pragma unroll 8
    for (int u = 0; u < 64; ++u) av += ag[b][64 + 3 * u + c1] * l2v[u * 32 + w1];
#pragma unroll 8
    for (int k = 0; k < 256; ++k) svv += opv[c1 * 256 + k] * scv[k * 32 + w1];
    float ov1 = av * 0.03125f + svv * 0.0625f;
    int f2 = 64 + l;
    int w2 = f2 / 3, c2 = f2 - 3 * w2;
    float av2 = 0.f, sv2 = 0.f;
    if (l < 32) {
#pragma unroll 8
      for (int u = 0; u < 64; ++u) av2 += ag[b][64 + 3 * u + c2] * l2v[u * 32 + w2];
#pragma unroll 8
      for (int k = 0; k < 256; ++k) sv2 += opv[c2 * 256 + k] * scv[k * 32 + w2];
    }
    float ov2 = av2 * 0.03125f + sv2 * 0.0625f;
    float gate1 = __shfl(gss, 32 + w1, 64);
    float gate2 = __shfl(gss, 32 + w2, 64);
    float* o = out + (size_t)nd * 128;
    if (l < 32) o[l] = xa[b][l] + gss;
    o[32 + l] = xa[b][32 + l] + ov1 * gate1;
    if (l < 32) o[96 + l] = xa[b][96 + l] + ov2 * gate2;
    __syncthreads();
  }
}

extern "C" void kernel_launch(void* const* d_in, const int* in_sizes, int n_in,
                              void* d_out, int out_size, void* d_ws, size_t ws_size,
                              hipStream_t stream) {
  const float* node_input = (const float*)d_in[0];
  const float* node_attr  = (const float*)d_in[1];
  const int*   esrc  = (const int*)d_in[2];
  const int*   edst  = (const int*)d_in[3];
  const float* eattr = (const float*)d_in[4];
  const float* escal = (const float*)d_in[5];
  const float* l1s = (const float*)d_in[6];
  const float* l1v = (const float*)d_in[7];
  const float* w1  = (const float*)d_in[8];
  const float* w2  = (const float*)d_in[9];
  const float* w3  = (const float*)d_in[10];
  const float* l2s = (const float*)d_in[11];
  const float* l2v = (const float*)d_in[12];
  const float* scs = (const float*)d_in[13];
  const float* scv = (const float*)d_in[14];
  float* out  = (float*)d_out;

  float* s1v1 = (float*)d_ws;                                  // 30000*128 f32
  float* agg  = s1v1 + (size_t)N_NODES * 128;                  // 30000*256 f32
  int* counts    = (int*)(agg + (size_t)N_NODES * 256);        // 30000
  int* row_start = counts + N_NODES;                           // 30001
  int* cursor    = row_start + N_NODES + 1;                    // 30000
  int* eidx      = cursor + N_NODES;                           // 480000

  // CSR build (edge_dst is layer-invariant)
  hipMemsetAsync(counts, 0, (size_t)N_NODES * sizeof(int), stream);
  k_hist<<<(N_EDGES + 255) / 256, 256, 0, stream>>>(edst, counts);
  k_scan<<<1, SCAN_T, 0, stream>>>(counts, row_start, cursor);
  k_scatter<<<(N_EDGES + 255) / 256, 256, 0, stream>>>(edst, cursor, eidx);

  for (int layer = 0; layer < 3; ++layer) {
    const float* xin = (layer == 0) ? node_input : (const float*)out;
    k_node_pre<<<N_NODES * 128 / 256, 256, 0, stream>>>(
        xin, l1s + layer * 1024, l1v + layer * 1024, s1v1);
    k_edge_agg<<<N_NODES / 4, 256, 0, stream>>>(escal, esrc, eattr, s1v1,
        row_start, eidx, w1 + layer * 512, w2 + layer * 4096, w3 + layer * 8192, agg);
    k_node_post<<<N_NODES / 4, 64, 0, stream>>>(xin, node_attr, agg,
        l2s + layer * 4096, l2v + layer * 2048, scs + layer * 16384, scv + layer * 8192, out);
  }
}

// Round 4
// 1924.574 us; speedup vs baseline: 2.0710x; 1.2825x over previous
//
#include <hip/hip_runtime.h>
#include <math.h>

#define N_NODES 30000
#define N_EDGES 480000

typedef __attribute__((ext_vector_type(8))) short s8v;   // 8 x bf16 (as i16 bits)
typedef __attribute__((ext_vector_type(4))) float f4v;

__device__ inline unsigned short f2bf(float f) {
  union { float f; unsigned u; } v; v.f = f;
  return (unsigned short)((v.u + 0x7fffu + ((v.u >> 16) & 1u)) >> 16);  // RNE
}
__device__ inline float bfh2f(unsigned short h) {
  union { unsigned u; float f; } v; v.u = (unsigned)h << 16; return v.f;
}
// fast softplus(x) - log2: max(x,0) + log(1+e^-|x|) - ln2, native exp/log (~7 VALU, no branches)
__device__ inline float sspf(float x) {
  float t = __expf(-fabsf(x));
  return fmaxf(x, 0.f) + __logf(1.f + t) - 0.69314718055994531f;
}

// ---------------- CSR build (once per launch; edge_dst identical across layers) ----------------
__global__ __launch_bounds__(256) void k_hist(const int* __restrict__ edst, int* __restrict__ counts) {
  int e = blockIdx.x * 256 + threadIdx.x;
  if (e < N_EDGES) atomicAdd(&counts[edst[e]], 1);
}

#define SCAN_T 1024
#define NPER 30   // 1024*30 = 30720 >= 30000
__global__ __launch_bounds__(1024) void k_scan(const int* __restrict__ counts,
                                               int* __restrict__ row_start, int* __restrict__ cursor) {
  __shared__ int part[SCAN_T];
  int t = threadIdx.x;
  int base = t * NPER;
  int local[NPER];
  int s = 0;
#pragma unroll
  for (int j = 0; j < NPER; ++j) {
    int idx = base + j;
    int c = (idx < N_NODES) ? counts[idx] : 0;
    local[j] = s;
    s += c;
  }
  part[t] = s;
  __syncthreads();
  for (int off = 1; off < SCAN_T; off <<= 1) {
    int v = (t >= off) ? part[t - off] : 0;
    __syncthreads();
    part[t] += v;
    __syncthreads();
  }
  int pre = (t == 0) ? 0 : part[t - 1];
#pragma unroll
  for (int j = 0; j < NPER; ++j) {
    int idx = base + j;
    if (idx < N_NODES) {
      int v = pre + local[j];
      row_start[idx] = v;
      cursor[idx] = v;
    }
  }
  if (t == SCAN_T - 1) row_start[N_NODES] = pre + s;
}

__global__ __launch_bounds__(256) void k_scatter(const int* __restrict__ edst,
                                                 int* __restrict__ cursor, int* __restrict__ eidx) {
  int e = blockIdx.x * 256 + threadIdx.x;
  if (e < N_EDGES) {
    int pos = atomicAdd(&cursor[edst[e]], 1);
    eidx[pos] = e;
  }
}

// sort each node's segment ascending -> eidx fully deterministic (atomic order erased)
__global__ __launch_bounds__(256) void k_sortseg(const int* __restrict__ row_start, int* __restrict__ eidx) {
  int n = blockIdx.x * 256 + threadIdx.x;
  if (n >= N_NODES) return;
  int jb = row_start[n], je = row_start[n + 1];
  for (int i = jb + 1; i < je; ++i) {
    int v = eidx[i];
    int j = i - 1;
    while (j >= jb && eidx[j] > v) { eidx[j + 1] = eidx[j]; --j; }
    eidx[j + 1] = v;
  }
}

// ---------------- node_pre: s1 = s@lin1_s/sqrt32 ; v1 = v@lin1_v/sqrt32 ----------------
__global__ __launch_bounds__(256) void k_node_pre(const float* __restrict__ x,
    const float* __restrict__ l1s, const float* __restrict__ l1v,
    float* __restrict__ s1v1)
{
  int t = blockIdx.x * 256 + threadIdx.x;
  int node = t >> 7, j = t & 127;
  const float* xr = x + (size_t)node * 128;
  float acc = 0.f;
  if (j < 32) {
#pragma unroll
    for (int u = 0; u < 32; ++u) acc += xr[u] * l1s[u * 32 + j];
  } else {
    int jj = j - 32, m = jj / 3, c = jj - 3 * m;
#pragma unroll
    for (int u = 0; u < 32; ++u) acc += xr[32 + u * 3 + c] * l1v[u * 32 + m];
  }
  s1v1[t] = acc * 0.17677669529663689f;
}

// ---------------- fused edge MLP + per-node aggregation (1 wave = 1 dst node, no atomics) ----------
// Activations (esc,h1,h2) carried as hi+lo bf16 pairs -> A-side numerically exact; W1 also split
// (fits K=32 pad). Residual error = W2/W3 bf16 rounding only (~2^-9 rel).
// MFMA frags: A row=lane&15, k=8*(lane>>4)+i. B col=lane&15. C/D col=lane&15, row=(lane>>4)*4+i.
__global__ __launch_bounds__(256, 2) void k_edge_agg(
    const float* __restrict__ esc, const int* __restrict__ esrc,
    const float* __restrict__ eattr, const float* __restrict__ s1v1,
    const int* __restrict__ row_start, const int* __restrict__ eidx,
    const float* __restrict__ w1g, const float* __restrict__ w2g, const float* __restrict__ w3g,
    float* __restrict__ agg)
{
  __shared__ __attribute__((aligned(16))) unsigned short W2T[64 * 72];    // [n][k] padded
  __shared__ __attribute__((aligned(16))) unsigned short W3T[128 * 72];   // [n][k] padded
  __shared__ __attribute__((aligned(16))) unsigned short Hb[4][4][16 * 72]; // [wv][h1hi,h1lo,h2hi,h2lo]

  const int tid = threadIdx.x, lane = tid & 63, wv = tid >> 6;
  const int c0 = lane & 15, g = lane >> 4;

  for (int idx = tid; idx < 64 * 64; idx += 256) {
    int k = idx >> 6, n2 = idx & 63;
    W2T[n2 * 72 + k] = f2bf(w2g[idx]);
  }
  for (int idx = tid; idx < 64 * 128; idx += 256) {
    int k = idx >> 7, n2 = idx & 127;
    W3T[n2 * 72 + k] = f2bf(w3g[idx]);
  }
  // B1: k-groups g=0,1 -> W1_hi rows; g=2,3 -> W1_lo rows
  s8v B1[4];
#pragma unroll
  for (int nt = 0; nt < 4; ++nt)
#pragma unroll
    for (int i = 0; i < 8; ++i) {
      float w = w1g[i * 64 + nt * 16 + c0];
      unsigned short hi = f2bf(w);
      B1[nt][i] = (g < 2) ? (short)hi : (short)f2bf(w - bfh2f(hi));
    }
  __syncthreads();   // only block-wide barrier (waves diverge after this)

  unsigned short* h1hi = &Hb[wv][0][0];
  unsigned short* h1lo = &Hb[wv][1][0];
  unsigned short* h2hi = &Hb[wv][2][0];
  unsigned short* h2lo = &Hb[wv][3][0];
  const f4v z = {0.f, 0.f, 0.f, 0.f};

  const int node = blockIdx.x * 4 + wv;
  const int jb = row_start[node], je = row_start[node + 1];

  float nacc[16];
#pragma unroll
  for (int k = 0; k < 16; ++k) nacc[k] = 0.f;

  for (int base = jb; base < je; base += 16) {
    const int nvalid = je - base;
    // ---- stage 1: h1 = ssp(es @ W1 / sqrt(8)); A k-groups: g even -> esc_hi, g odd -> esc_lo
    s8v A1 = {0, 0, 0, 0, 0, 0, 0, 0};
    if (c0 < nvalid) {
      int eid = eidx[base + c0];
      const float4* p = (const float4*)(esc + (size_t)eid * 8);
      float4 a = p[0], b = p[1];
      float e8[8] = {a.x, a.y, a.z, a.w, b.x, b.y, b.z, b.w};
#pragma unroll
      for (int j = 0; j < 8; ++j) {
        unsigned short hi = f2bf(e8[j]);
        A1[j] = (g & 1) ? (short)f2bf(e8[j] - bfh2f(hi)) : (short)hi;
      }
    }
#pragma unroll
    for (int nt = 0; nt < 4; ++nt) {
      f4v acc = __builtin_amdgcn_mfma_f32_16x16x32_bf16(A1, B1[nt], z, 0, 0, 0);
#pragma unroll
      for (int i = 0; i < 4; ++i) {
        float hv = sspf(acc[i] * 0.35355339059327373f);
        unsigned short hi = f2bf(hv);
        h1hi[(g * 4 + i) * 72 + nt * 16 + c0] = hi;
        h1lo[(g * 4 + i) * 72 + nt * 16 + c0] = f2bf(hv - bfh2f(hi));
      }
    }
    // ---- stage 2: h2 = ssp(h1 @ W2 / 8)   (in-wave LDS dep; in-order DS + lgkmcnt)
    s8v A2ah = *(const s8v*)&h1hi[c0 * 72 + 8 * g];
    s8v A2bh = *(const s8v*)&h1hi[c0 * 72 + 32 + 8 * g];
    s8v A2al = *(const s8v*)&h1lo[c0 * 72 + 8 * g];
    s8v A2bl = *(const s8v*)&h1lo[c0 * 72 + 32 + 8 * g];
#pragma unroll
    for (int nt = 0; nt < 4; ++nt) {
      s8v Ba = *(const s8v*)&W2T[(nt * 16 + c0) * 72 + 8 * g];
      s8v Bb = *(const s8v*)&W2T[(nt * 16 + c0) * 72 + 32 + 8 * g];
      f4v acc = __builtin_amdgcn_mfma_f32_16x16x32_bf16(A2ah, Ba, z, 0, 0, 0);
      acc = __builtin_amdgcn_mfma_f32_16x16x32_bf16(A2bh, Bb, acc, 0, 0, 0);
      acc = __builtin_amdgcn_mfma_f32_16x16x32_bf16(A2al, Ba, acc, 0, 0, 0);
      acc = __builtin_amdgcn_mfma_f32_16x16x32_bf16(A2bl, Bb, acc, 0, 0, 0);
#pragma unroll
      for (int i = 0; i < 4; ++i) {
        float hv = sspf(acc[i] * 0.125f);
        unsigned short hi = f2bf(hv);
        h2hi[(g * 4 + i) * 72 + nt * 16 + c0] = hi;
        h2lo[(g * 4 + i) * 72 + nt * 16 + c0] = f2bf(hv - bfh2f(hi));
      }
    }
    // ---- stage 3: w = h2 @ W3 / 8
    s8v A3ah = *(const s8v*)&h2hi[c0 * 72 + 8 * g];
    s8v A3bh = *(const s8v*)&h2hi[c0 * 72 + 32 + 8 * g];
    s8v A3al = *(const s8v*)&h2lo[c0 * 72 + 8 * g];
    s8v A3bl = *(const s8v*)&h2lo[c0 * 72 + 32 + 8 * g];
    f4v acc3[8];
#pragma unroll
    for (int nt = 0; nt < 8; ++nt) {
      s8v Ba = *(const s8v*)&W3T[(nt * 16 + c0) * 72 + 8 * g];
      s8v Bb = *(const s8v*)&W3T[(nt * 16 + c0) * 72 + 32 + 8 * g];
      acc3[nt] = __builtin_amdgcn_mfma_f32_16x16x32_bf16(A3ah, Ba, z, 0, 0, 0);
      acc3[nt] = __builtin_amdgcn_mfma_f32_16x16x32_bf16(A3bh, Bb, acc3[nt], 0, 0, 0);
      acc3[nt] = __builtin_amdgcn_mfma_f32_16x16x32_bf16(A3al, Ba, acc3[nt], 0, 0, 0);
      acc3[nt] = __builtin_amdgcn_mfma_f32_16x16x32_bf16(A3bl, Bb, acc3[nt], 0, 0, 0);
    }
    // ---- epilogue: per-lane message partials for mA=c0, mB=c0+16 over this lane's 4 edge rows
    float msg[16];
#pragma unroll
    for (int k = 0; k < 16; ++k) msg[k] = 0.f;
#pragma unroll
    for (int i = 0; i < 4; ++i) {
      int s = g * 4 + i;
      float w0 = acc3[0][i] * 0.125f, w1_ = acc3[1][i] * 0.125f;
      float w2_ = acc3[2][i] * 0.125f, w3_ = acc3[3][i] * 0.125f;
      float w4_ = acc3[4][i] * 0.125f, w5_ = acc3[5][i] * 0.125f;
      float w6_ = acc3[6][i] * 0.125f, w7_ = acc3[7][i] * 0.125f;
      if (s < nvalid) {
        int eid = eidx[base + s];
        int src = esrc[eid];
        float4 y = *(const float4*)(eattr + (size_t)eid * 4);
        const float* svp = s1v1 + (size_t)src * 128;
        float sA = svp[c0], sB = svp[c0 + 16];
        float vA0 = svp[32 + 3 * c0], vA1 = svp[33 + 3 * c0], vA2 = svp[34 + 3 * c0];
        float vB0 = svp[80 + 3 * c0], vB1 = svp[81 + 3 * c0], vB2 = svp[82 + 3 * c0];
        msg[0] += w0 * sA * y.x;
        msg[1] += w1_ * sB * y.x;
        msg[2] += w6_ * (vA0 * y.y + vA1 * y.z + vA2 * y.w);
        msg[3] += w7_ * (vB0 * y.y + vB1 * y.z + vB2 * y.w);
        msg[4] += w2_ * sA * y.y;  msg[5] += w2_ * sA * y.z;  msg[6] += w2_ * sA * y.w;
        msg[7] += w3_ * sB * y.y;  msg[8] += w3_ * sB * y.z;  msg[9] += w3_ * sB * y.w;
        msg[10] += w4_ * vA0 * y.x; msg[11] += w4_ * vA1 * y.x; msg[12] += w4_ * vA2 * y.x;
        msg[13] += w5_ * vB0 * y.x; msg[14] += w5_ * vB1 * y.x; msg[15] += w5_ * vB2 * y.x;
      }
    }
#pragma unroll
    for (int k = 0; k < 16; ++k) {
      float v = msg[k];
      v += __shfl_xor(v, 16, 64);
      v += __shfl_xor(v, 32, 64);
      nacc[k] += v;
    }
  }
  if (g == 0) {
    float* ad = agg + (size_t)node * 256;
    ad[c0] = nacc[0];
    ad[16 + c0] = nacc[1];
    ad[32 + c0] = nacc[2];
    ad[48 + c0] = nacc[3];
#pragma unroll
    for (int c = 0; c < 3; ++c) {
      ad[64 + 3 * c0 + c]  = nacc[4 + c];
      ad[112 + 3 * c0 + c] = nacc[7 + c];
      ad[160 + 3 * c0 + c] = nacc[10 + c];
      ad[208 + 3 * c0 + c] = nacc[13 + c];
    }
  }
}

// ---------------- node_post: lin2 + self-connection + gate + residual ----------------
// 256 threads = 4 waves; each wave owns 4 nodes; per-wave LDS, no block barriers.
__global__ __launch_bounds__(256) void k_node_post(
    const float* __restrict__ x, const float* __restrict__ attr, const float* __restrict__ agg,
    const float* __restrict__ l2s, const float* __restrict__ l2v,
    const float* __restrict__ scs, const float* __restrict__ scv,
    float* __restrict__ out)
{
  __shared__ float xa[4][4][136];
  __shared__ float ag[4][4][256];
  __shared__ float ops[4][256];
  __shared__ float opv[4][768];
  const int l = threadIdx.x & 63, wv = threadIdx.x >> 6;
  const int n0 = blockIdx.x * 16 + wv * 4;
#pragma unroll
  for (int b = 0; b < 4; ++b) {
    int nd = n0 + b;
    xa[wv][b][l] = x[(size_t)nd * 128 + l];
    xa[wv][b][64 + l] = x[(size_t)nd * 128 + 64 + l];
    if (l < 8) xa[wv][b][128 + l] = attr[nd * 8 + l];
#pragma unroll
    for (int q = 0; q < 4; ++q) ag[wv][b][q * 64 + l] = agg[(size_t)nd * 256 + q * 64 + l];
  }
  for (int b = 0; b < 4; ++b) {
    int nd = n0 + b;
    for (int k = l; k < 256; k += 64) { int u = k >> 3, a = k & 7; ops[wv][k] = xa[wv][b][u] * xa[wv][b][128 + a]; }
    for (int k = l; k < 768; k += 64) {
      int c = k >> 8, kk = k & 255; int u = kk >> 3, a = kk & 7;
      opv[wv][k] = xa[wv][b][32 + 3 * u + c] * xa[wv][b][128 + a];
    }
    float acc = 0.f, sa = 0.f;
#pragma unroll 8
    for (int u = 0; u < 64; ++u) acc += ag[wv][b][u] * l2s[u * 64 + l];
#pragma unroll 8
    for (int k = 0; k < 256; ++k) sa += ops[wv][k] * scs[k * 64 + l];
    float outs = acc * 0.03125f + sa * 0.0625f;
    float gss = sspf(outs);
    int w1 = l / 3, c1 = l - 3 * w1;
    float av = 0.f, svv = 0.f;
#pragma unroll 8
    for (int u = 0; u < 64; ++u) av += ag[wv][b][64 + 3 * u + c1] * l2v[u * 32 + w1];
#pragma unroll 8
    for (int k = 0; k < 256; ++k) svv += opv[wv][c1 * 256 + k] * scv[k * 32 + w1];
    float ov1 = av * 0.03125f + svv * 0.0625f;
    int f2 = 64 + l;
    int w2 = f2 / 3, c2 = f2 - 3 * w2;
    float av2 = 0.f, sv2 = 0.f;
    if (l < 32) {
#pragma unroll 8
      for (int u = 0; u < 64; ++u) av2 += ag[wv][b][64 + 3 * u + c2] * l2v[u * 32 + w2];
#pragma unroll 8
      for (int k = 0; k < 256; ++k) sv2 += opv[wv][c2 * 256 + k] * scv[k * 32 + w2];
    }
    float ov2 = av2 * 0.03125f + sv2 * 0.0625f;
    float gate1 = __shfl(gss, 32 + w1, 64);
    float gate2 = __shfl(gss, 32 + w2, 64);
    float* o = out + (size_t)nd * 128;
    if (l < 32) o[l] = xa[wv][b][l] + gss;
    o[32 + l] = xa[wv][b][32 + l] + ov1 * gate1;
    if (l < 32) o[96 + l] = xa[wv][b][96 + l] + ov2 * gate2;
  }
}

extern "C" void kernel_launch(void* const* d_in, const int* in_sizes, int n_in,
                              void* d_out, int out_size, void* d_ws, size_t ws_size,
                              hipStream_t stream) {
  const float* node_input = (const float*)d_in[0];
  const float* node_attr  = (const float*)d_in[1];
  const int*   esrc  = (const int*)d_in[2];
  const int*   edst  = (const int*)d_in[3];
  const float* eattr = (const float*)d_in[4];
  const float* escal = (const float*)d_in[5];
  const float* l1s = (const float*)d_in[6];
  const float* l1v = (const float*)d_in[7];
  const float* w1  = (const float*)d_in[8];
  const float* w2  = (const float*)d_in[9];
  const float* w3  = (const float*)d_in[10];
  const float* l2s = (const float*)d_in[11];
  const float* l2v = (const float*)d_in[12];
  const float* scs = (const float*)d_in[13];
  const float* scv = (const float*)d_in[14];
  float* out  = (float*)d_out;

  float* s1v1 = (float*)d_ws;                                  // 30000*128 f32
  float* agg  = s1v1 + (size_t)N_NODES * 128;                  // 30000*256 f32
  int* counts    = (int*)(agg + (size_t)N_NODES * 256);        // 30000
  int* row_start = counts + N_NODES;                           // 30001
  int* cursor    = row_start + N_NODES + 1;                    // 30000
  int* eidx      = cursor + N_NODES;                           // 480000

  hipMemsetAsync(counts, 0, (size_t)N_NODES * sizeof(int), stream);
  k_hist<<<(N_EDGES + 255) / 256, 256, 0, stream>>>(edst, counts);
  k_scan<<<1, SCAN_T, 0, stream>>>(counts, row_start, cursor);
  k_scatter<<<(N_EDGES + 255) / 256, 256, 0, stream>>>(edst, cursor, eidx);
  k_sortseg<<<(N_NODES + 255) / 256, 256, 0, stream>>>(row_start, eidx);

  for (int layer = 0; layer < 3; ++layer) {
    const float* xin = (layer == 0) ? node_input : (const float*)out;
    k_node_pre<<<N_NODES * 128 / 256, 256, 0, stream>>>(
        xin, l1s + layer * 1024, l1v + layer * 1024, s1v1);
    k_edge_agg<<<N_NODES / 4, 256, 0, stream>>>(escal, esrc, eattr, s1v1,
        row_start, eidx, w1 + layer * 512, w2 + layer * 4096, w3 + layer * 8192, agg);
    k_node_post<<<N_NODES / 16, 256, 0, stream>>>(xin, node_attr, agg,
        l2s + layer * 4096, l2v + layer * 2048, scs + layer * 16384, scv + layer * 8192, out);
  }
}

// Round 5
// 1339.699 us; speedup vs baseline: 2.9752x; 1.4366x over previous
//
#include <hip/hip_runtime.h>
#include <math.h>

#define N_NODES 30000
#define N_EDGES 480000

typedef __attribute__((ext_vector_type(8))) short s8v;   // 8 x bf16 (as i16 bits)
typedef __attribute__((ext_vector_type(4))) float f4v;

__device__ inline unsigned short f2bf(float f) {
  union { float f; unsigned u; } v; v.f = f;
  return (unsigned short)((v.u + 0x7fffu + ((v.u >> 16) & 1u)) >> 16);  // RNE
}
__device__ inline float bfh2f(unsigned short h) {
  union { unsigned u; float f; } v; v.u = (unsigned)h << 16; return v.f;
}
// fast softplus(x) - log2: max(x,0) + log(1+e^-|x|) - ln2, native exp/log
__device__ inline float sspf(float x) {
  float t = __expf(-fabsf(x));
  return fmaxf(x, 0.f) + __logf(1.f + t) - 0.69314718055994531f;
}

// ---------------- CSR build (once per launch; edge_dst identical across layers) ----------------
__global__ __launch_bounds__(256) void k_hist(const int* __restrict__ edst, int* __restrict__ counts) {
  int e = blockIdx.x * 256 + threadIdx.x;
  if (e < N_EDGES) atomicAdd(&counts[edst[e]], 1);
}

#define SCAN_T 1024
#define NPER 30   // 1024*30 = 30720 >= 30000
__global__ __launch_bounds__(1024) void k_scan(const int* __restrict__ counts,
                                               int* __restrict__ row_start, int* __restrict__ cursor) {
  __shared__ int part[SCAN_T];
  int t = threadIdx.x;
  int base = t * NPER;
  int local[NPER];
  int s = 0;
#pragma unroll
  for (int j = 0; j < NPER; ++j) {
    int idx = base + j;
    int c = (idx < N_NODES) ? counts[idx] : 0;
    local[j] = s;
    s += c;
  }
  part[t] = s;
  __syncthreads();
  for (int off = 1; off < SCAN_T; off <<= 1) {
    int v = (t >= off) ? part[t - off] : 0;
    __syncthreads();
    part[t] += v;
    __syncthreads();
  }
  int pre = (t == 0) ? 0 : part[t - 1];
#pragma unroll
  for (int j = 0; j < NPER; ++j) {
    int idx = base + j;
    if (idx < N_NODES) {
      int v = pre + local[j];
      row_start[idx] = v;
      cursor[idx] = v;
    }
  }
  if (t == SCAN_T - 1) row_start[N_NODES] = pre + s;
}

__global__ __launch_bounds__(256) void k_scatter(const int* __restrict__ edst,
                                                 int* __restrict__ cursor, int* __restrict__ eidx) {
  int e = blockIdx.x * 256 + threadIdx.x;
  if (e < N_EDGES) {
    int pos = atomicAdd(&cursor[edst[e]], 1);
    eidx[pos] = e;
  }
}

// sort each node's segment ascending -> eidx fully deterministic (atomic order erased)
__global__ __launch_bounds__(256) void k_sortseg(const int* __restrict__ row_start, int* __restrict__ eidx) {
  int n = blockIdx.x * 256 + threadIdx.x;
  if (n >= N_NODES) return;
  int jb = row_start[n], je = row_start[n + 1];
  for (int i = jb + 1; i < je; ++i) {
    int v = eidx[i];
    int j = i - 1;
    while (j >= jb && eidx[j] > v) { eidx[j + 1] = eidx[j]; --j; }
    eidx[j + 1] = v;
  }
}

// ---------------- node_pre: s1 = s@lin1_s/sqrt32 ; v1 = v@lin1_v/sqrt32 ----------------
__global__ __launch_bounds__(256) void k_node_pre(const float* __restrict__ x,
    const float* __restrict__ l1s, const float* __restrict__ l1v,
    float* __restrict__ s1v1)
{
  int t = blockIdx.x * 256 + threadIdx.x;
  int node = t >> 7, j = t & 127;
  const float* xr = x + (size_t)node * 128;
  float acc = 0.f;
  if (j < 32) {
#pragma unroll
    for (int u = 0; u < 32; ++u) acc += xr[u] * l1s[u * 32 + j];
  } else {
    int jj = j - 32, m = jj / 3, c = jj - 3 * m;
#pragma unroll
    for (int u = 0; u < 32; ++u) acc += xr[32 + u * 3 + c] * l1v[u * 32 + m];
  }
  s1v1[t] = acc * 0.17677669529663689f;
}

// ---------------- fused edge MLP + per-node aggregation (1 wave = 1 dst node, no atomics) ----------
// Activations carried as hi+lo bf16 pairs; W1 split into the K=32 pad. One shared h-buffer per wave
// is reused for h1 then h2 (per-wave in-order DS: reads precede overwrites). LDS 46.1KB -> 3 blk/CU.
__global__ __launch_bounds__(256, 3) void k_edge_agg(
    const float* __restrict__ esc, const int* __restrict__ esrc,
    const float* __restrict__ eattr, const float* __restrict__ s1v1,
    const int* __restrict__ row_start, const int* __restrict__ eidx,
    const float* __restrict__ w1g, const float* __restrict__ w2g, const float* __restrict__ w3g,
    float* __restrict__ agg)
{
  __shared__ __attribute__((aligned(16))) unsigned short W2T[64 * 72];    // [n][k] padded
  __shared__ __attribute__((aligned(16))) unsigned short W3T[128 * 72];   // [n][k] padded
  __shared__ __attribute__((aligned(16))) unsigned short Hb[4][2][16 * 72]; // [wv][hi,lo] reused h1->h2

  const int tid = threadIdx.x, lane = tid & 63, wv = tid >> 6;
  const int c0 = lane & 15, g = lane >> 4;

  for (int idx = tid; idx < 64 * 64; idx += 256) {
    int k = idx >> 6, n2 = idx & 63;
    W2T[n2 * 72 + k] = f2bf(w2g[idx]);
  }
  for (int idx = tid; idx < 64 * 128; idx += 256) {
    int k = idx >> 7, n2 = idx & 127;
    W3T[n2 * 72 + k] = f2bf(w3g[idx]);
  }
  // B1: k-groups g=0,1 -> W1_hi rows; g=2,3 -> W1_lo rows
  s8v B1[4];
#pragma unroll
  for (int nt = 0; nt < 4; ++nt)
#pragma unroll
    for (int i = 0; i < 8; ++i) {
      float w = w1g[i * 64 + nt * 16 + c0];
      unsigned short hi = f2bf(w);
      B1[nt][i] = (g < 2) ? (short)hi : (short)f2bf(w - bfh2f(hi));
    }
  __syncthreads();   // only block-wide barrier (waves diverge after this)

  unsigned short* hhi = &Hb[wv][0][0];
  unsigned short* hlo = &Hb[wv][1][0];
  const f4v z = {0.f, 0.f, 0.f, 0.f};

  const int node = blockIdx.x * 4 + wv;
  const int jb = row_start[node], je = row_start[node + 1];

  float nacc[16];
#pragma unroll
  for (int k = 0; k < 16; ++k) nacc[k] = 0.f;

  for (int base = jb; base < je; base += 16) {
    const int nvalid = je - base;
    // ---- stage 1: h1 = ssp(es @ W1 / sqrt(8)); A k-groups: g even -> esc_hi, g odd -> esc_lo
    s8v A1 = {0, 0, 0, 0, 0, 0, 0, 0};
    if (c0 < nvalid) {
      int eid = eidx[base + c0];
      const float4* p = (const float4*)(esc + (size_t)eid * 8);
      float4 a = p[0], b = p[1];
      float e8[8] = {a.x, a.y, a.z, a.w, b.x, b.y, b.z, b.w};
#pragma unroll
      for (int j = 0; j < 8; ++j) {
        unsigned short hi = f2bf(e8[j]);
        A1[j] = (g & 1) ? (short)f2bf(e8[j] - bfh2f(hi)) : (short)hi;
      }
    }
#pragma unroll
    for (int nt = 0; nt < 4; ++nt) {
      f4v acc = __builtin_amdgcn_mfma_f32_16x16x32_bf16(A1, B1[nt], z, 0, 0, 0);
#pragma unroll
      for (int i = 0; i < 4; ++i) {
        float hv = sspf(acc[i] * 0.35355339059327373f);
        unsigned short hi = f2bf(hv);
        hhi[(g * 4 + i) * 72 + nt * 16 + c0] = hi;
        hlo[(g * 4 + i) * 72 + nt * 16 + c0] = f2bf(hv - bfh2f(hi));
      }
    }
    // ---- stage 2: h2 = ssp(h1 @ W2 / 8). A2 frags fully loaded before h2 overwrites the buffer.
    s8v A2ah = *(const s8v*)&hhi[c0 * 72 + 8 * g];
    s8v A2bh = *(const s8v*)&hhi[c0 * 72 + 32 + 8 * g];
    s8v A2al = *(const s8v*)&hlo[c0 * 72 + 8 * g];
    s8v A2bl = *(const s8v*)&hlo[c0 * 72 + 32 + 8 * g];
#pragma unroll
    for (int nt = 0; nt < 4; ++nt) {
      s8v Ba = *(const s8v*)&W2T[(nt * 16 + c0) * 72 + 8 * g];
      s8v Bb = *(const s8v*)&W2T[(nt * 16 + c0) * 72 + 32 + 8 * g];
      f4v acc = __builtin_amdgcn_mfma_f32_16x16x32_bf16(A2ah, Ba, z, 0, 0, 0);
      acc = __builtin_amdgcn_mfma_f32_16x16x32_bf16(A2bh, Bb, acc, 0, 0, 0);
      acc = __builtin_amdgcn_mfma_f32_16x16x32_bf16(A2al, Ba, acc, 0, 0, 0);
      acc = __builtin_amdgcn_mfma_f32_16x16x32_bf16(A2bl, Bb, acc, 0, 0, 0);
#pragma unroll
      for (int i = 0; i < 4; ++i) {
        float hv = sspf(acc[i] * 0.125f);
        unsigned short hi = f2bf(hv);
        hhi[(g * 4 + i) * 72 + nt * 16 + c0] = hi;
        hlo[(g * 4 + i) * 72 + nt * 16 + c0] = f2bf(hv - bfh2f(hi));
      }
    }
    // ---- stage 3: w = h2 @ W3 / 8
    s8v A3ah = *(const s8v*)&hhi[c0 * 72 + 8 * g];
    s8v A3bh = *(const s8v*)&hhi[c0 * 72 + 32 + 8 * g];
    s8v A3al = *(const s8v*)&hlo[c0 * 72 + 8 * g];
    s8v A3bl = *(const s8v*)&hlo[c0 * 72 + 32 + 8 * g];
    f4v acc3[8];
#pragma unroll
    for (int nt = 0; nt < 8; ++nt) {
      s8v Ba = *(const s8v*)&W3T[(nt * 16 + c0) * 72 + 8 * g];
      s8v Bb = *(const s8v*)&W3T[(nt * 16 + c0) * 72 + 32 + 8 * g];
      acc3[nt] = __builtin_amdgcn_mfma_f32_16x16x32_bf16(A3ah, Ba, z, 0, 0, 0);
      acc3[nt] = __builtin_amdgcn_mfma_f32_16x16x32_bf16(A3bh, Bb, acc3[nt], 0, 0, 0);
      acc3[nt] = __builtin_amdgcn_mfma_f32_16x16x32_bf16(A3al, Ba, acc3[nt], 0, 0, 0);
      acc3[nt] = __builtin_amdgcn_mfma_f32_16x16x32_bf16(A3bl, Bb, acc3[nt], 0, 0, 0);
    }
    // ---- epilogue: per-lane message partials for mA=c0, mB=c0+16 over this lane's 4 edge rows
    float msg[16];
#pragma unroll
    for (int k = 0; k < 16; ++k) msg[k] = 0.f;
#pragma unroll
    for (int i = 0; i < 4; ++i) {
      int s = g * 4 + i;
      float w0 = acc3[0][i] * 0.125f, w1_ = acc3[1][i] * 0.125f;
      float w2_ = acc3[2][i] * 0.125f, w3_ = acc3[3][i] * 0.125f;
      float w4_ = acc3[4][i] * 0.125f, w5_ = acc3[5][i] * 0.125f;
      float w6_ = acc3[6][i] * 0.125f, w7_ = acc3[7][i] * 0.125f;
      if (s < nvalid) {
        int eid = eidx[base + s];
        int src = esrc[eid];
        float4 y = *(const float4*)(eattr + (size_t)eid * 4);
        const float* svp = s1v1 + (size_t)src * 128;
        float sA = svp[c0], sB = svp[c0 + 16];
        float vA0 = svp[32 + 3 * c0], vA1 = svp[33 + 3 * c0], vA2 = svp[34 + 3 * c0];
        float vB0 = svp[80 + 3 * c0], vB1 = svp[81 + 3 * c0], vB2 = svp[82 + 3 * c0];
        msg[0] += w0 * sA * y.x;
        msg[1] += w1_ * sB * y.x;
        msg[2] += w6_ * (vA0 * y.y + vA1 * y.z + vA2 * y.w);
        msg[3] += w7_ * (vB0 * y.y + vB1 * y.z + vB2 * y.w);
        msg[4] += w2_ * sA * y.y;  msg[5] += w2_ * sA * y.z;  msg[6] += w2_ * sA * y.w;
        msg[7] += w3_ * sB * y.y;  msg[8] += w3_ * sB * y.z;  msg[9] += w3_ * sB * y.w;
        msg[10] += w4_ * vA0 * y.x; msg[11] += w4_ * vA1 * y.x; msg[12] += w4_ * vA2 * y.x;
        msg[13] += w5_ * vB0 * y.x; msg[14] += w5_ * vB1 * y.x; msg[15] += w5_ * vB2 * y.x;
      }
    }
#pragma unroll
    for (int k = 0; k < 16; ++k) {
      float v = msg[k];
      v += __shfl_xor(v, 16, 64);
      v += __shfl_xor(v, 32, 64);
      nacc[k] += v;
    }
  }
  if (g == 0) {
    float* ad = agg + (size_t)node * 256;
    ad[c0] = nacc[0];
    ad[16 + c0] = nacc[1];
    ad[32 + c0] = nacc[2];
    ad[48 + c0] = nacc[3];
#pragma unroll
    for (int c = 0; c < 3; ++c) {
      ad[64 + 3 * c0 + c]  = nacc[4 + c];
      ad[112 + 3 * c0 + c] = nacc[7 + c];
      ad[160 + 3 * c0 + c] = nacc[10 + c];
      ad[208 + 3 * c0 + c] = nacc[13 + c];
    }
  }
}

// ---------------- node_post: lin2 + self-connection + gate + residual ----------------
// 256 threads = 4 waves; each wave owns 4 nodes REGISTER-BLOCKED: every weight load feeds 4 FMAs.
// attr cached in registers; s/v operands broadcast from per-wave LDS (conflict-free).
__global__ __launch_bounds__(256) void k_node_post(
    const float* __restrict__ x, const float* __restrict__ attr, const float* __restrict__ agg,
    const float* __restrict__ l2s, const float* __restrict__ l2v,
    const float* __restrict__ scs, const float* __restrict__ scv,
    float* __restrict__ out)
{
  __shared__ float xa[4][4][136];   // [wave][node] x row (128) + attr (8)
  __shared__ float ag[4][4][256];
  const int l = threadIdx.x & 63, wv = threadIdx.x >> 6;
  const int n0 = blockIdx.x * 16 + wv * 4;
#pragma unroll
  for (int b = 0; b < 4; ++b) {
    int nd = n0 + b;
    xa[wv][b][l] = x[(size_t)nd * 128 + l];
    xa[wv][b][64 + l] = x[(size_t)nd * 128 + 64 + l];
    if (l < 8) xa[wv][b][128 + l] = attr[nd * 8 + l];
#pragma unroll
    for (int q = 0; q < 4; ++q) ag[wv][b][q * 64 + l] = agg[(size_t)nd * 256 + q * 64 + l];
  }
  // per-wave LDS only; in-order DS per wave makes these reads safe without a barrier
  float attr_r[4][8];
#pragma unroll
  for (int b = 0; b < 4; ++b)
#pragma unroll
    for (int a = 0; a < 8; ++a) attr_r[b][a] = xa[wv][b][128 + a];

  // lane -> output mapping (as before): scalar col l; vec flats f1=l, f2=64+l (l<32)
  const int w1 = l / 3, c1 = l - 3 * w1;
  const int f2 = 64 + l;
  const int w2r = f2 / 3, c2r = f2 - 3 * w2r;
  const int w2 = (l < 32) ? w2r : 0, c2 = (l < 32) ? c2r : 0;   // clamped for safe addressing

  float acc[4] = {0.f, 0.f, 0.f, 0.f}, sa[4] = {0.f, 0.f, 0.f, 0.f};
  float av1[4] = {0.f, 0.f, 0.f, 0.f}, sv1[4] = {0.f, 0.f, 0.f, 0.f};
  float av2[4] = {0.f, 0.f, 0.f, 0.f}, sv2[4] = {0.f, 0.f, 0.f, 0.f};

  // lin2_s: K=64
#pragma unroll 8
  for (int u = 0; u < 64; ++u) {
    float wl = l2s[u * 64 + l];
#pragma unroll
    for (int b = 0; b < 4; ++b) acc[b] += ag[wv][b][u] * wl;
  }
  // lin2_v: K=64 (both vec outputs)
#pragma unroll 4
  for (int u = 0; u < 64; ++u) {
    float wla = l2v[u * 32 + w1];
    float wlb = l2v[u * 32 + w2];
#pragma unroll
    for (int b = 0; b < 4; ++b) {
      av1[b] += ag[wv][b][64 + 3 * u + c1] * wla;
      av2[b] += ag[wv][b][64 + 3 * u + c2] * wlb;
    }
  }
  // sc_s: K=256 = u(32) x a(8)
  for (int u = 0; u < 32; ++u) {
    float sb[4];
#pragma unroll
    for (int b = 0; b < 4; ++b) sb[b] = xa[wv][b][u];
#pragma unroll
    for (int a = 0; a < 8; ++a) {
      float wl = scs[(u * 8 + a) * 64 + l];
#pragma unroll
      for (int b = 0; b < 4; ++b) sa[b] += sb[b] * attr_r[b][a] * wl;
    }
  }
  // sc_v: K=256 (both vec outputs)
  for (int u = 0; u < 32; ++u) {
    float vb1[4], vb2[4];
#pragma unroll
    for (int b = 0; b < 4; ++b) {
      vb1[b] = xa[wv][b][32 + 3 * u + c1];
      vb2[b] = xa[wv][b][32 + 3 * u + c2];
    }
#pragma unroll
    for (int a = 0; a < 8; ++a) {
      float wla = scv[(u * 8 + a) * 32 + w1];
      float wlb = scv[(u * 8 + a) * 32 + w2];
#pragma unroll
      for (int b = 0; b < 4; ++b) {
        sv1[b] += vb1[b] * attr_r[b][a] * wla;
        sv2[b] += vb2[b] * attr_r[b][a] * wlb;
      }
    }
  }

#pragma unroll
  for (int b = 0; b < 4; ++b) {
    float outs = acc[b] * 0.03125f + sa[b] * 0.0625f;
    float gss = sspf(outs);
    float ov1 = av1[b] * 0.03125f + sv1[b] * 0.0625f;
    float ov2 = av2[b] * 0.03125f + sv2[b] * 0.0625f;
    float gate1 = __shfl(gss, 32 + w1, 64);
    float gate2 = __shfl(gss, 32 + w2, 64);
    float* o = out + (size_t)(n0 + b) * 128;
    if (l < 32) o[l] = xa[wv][b][l] + gss;
    o[32 + l] = xa[wv][b][32 + l] + ov1 * gate1;
    if (l < 32) o[96 + l] = xa[wv][b][96 + l] + ov2 * gate2;
  }
}

extern "C" void kernel_launch(void* const* d_in, const int* in_sizes, int n_in,
                              void* d_out, int out_size, void* d_ws, size_t ws_size,
                              hipStream_t stream) {
  const float* node_input = (const float*)d_in[0];
  const float* node_attr  = (const float*)d_in[1];
  const int*   esrc  = (const int*)d_in[2];
  const int*   edst  = (const int*)d_in[3];
  const float* eattr = (const float*)d_in[4];
  const float* escal = (const float*)d_in[5];
  const float* l1s = (const float*)d_in[6];
  const float* l1v = (const float*)d_in[7];
  const float* w1  = (const float*)d_in[8];
  const float* w2  = (const float*)d_in[9];
  const float* w3  = (const float*)d_in[10];
  const float* l2s = (const float*)d_in[11];
  const float* l2v = (const float*)d_in[12];
  const float* scs = (const float*)d_in[13];
  const float* scv = (const float*)d_in[14];
  float* out  = (float*)d_out;

  float* s1v1 = (float*)d_ws;                                  // 30000*128 f32
  float* agg  = s1v1 + (size_t)N_NODES * 128;                  // 30000*256 f32
  int* counts    = (int*)(agg + (size_t)N_NODES * 256);        // 30000
  int* row_start = counts + N_NODES;                           // 30001
  int* cursor    = row_start + N_NODES + 1;                    // 30000
  int* eidx      = cursor + N_NODES;                           // 480000

  hipMemsetAsync(counts, 0, (size_t)N_NODES * sizeof(int), stream);
  k_hist<<<(N_EDGES + 255) / 256, 256, 0, stream>>>(edst, counts);
  k_scan<<<1, SCAN_T, 0, stream>>>(counts, row_start, cursor);
  k_scatter<<<(N_EDGES + 255) / 256, 256, 0, stream>>>(edst, cursor, eidx);
  k_sortseg<<<(N_NODES + 255) / 256, 256, 0, stream>>>(row_start, eidx);

  for (int layer = 0; layer < 3; ++layer) {
    const float* xin = (layer == 0) ? node_input : (const float*)out;
    k_node_pre<<<N_NODES * 128 / 256, 256, 0, stream>>>(
        xin, l1s + layer * 1024, l1v + layer * 1024, s1v1);
    k_edge_agg<<<N_NODES / 4, 256, 0, stream>>>(escal, esrc, eattr, s1v1,
        row_start, eidx, w1 + layer * 512, w2 + layer * 4096, w3 + layer * 8192, agg);
    k_node_post<<<N_NODES / 16, 256, 0, stream>>>(xin, node_attr, agg,
        l2s + layer * 4096, l2v + layer * 2048, scs + layer * 16384, scv + layer * 8192, out);
  }
}